// Round 2
// baseline (3656.162 us; speedup 1.0000x reference)
//
#include <hip/hip_runtime.h>

// Receptor LSTM on MI355X — FUSED single-pass plan. f32 OUTPUT.
//  R2: x-GEMM fused into the recurrent kernel. xfrag intermediate (1.08 GB
//  HBM read + 1.08 GB write per run, L3-eviction-fragile) eliminated.
//  K_rec: 256 WGs = 8 bg x 32 jg, block 512 (8 waves). Each jg owns 32 chunks
//    + 4 warm chunks (truncated-history: residual 0.5/chunk + forget-gate
//    contraction => truncation error ~<1e-3 rel) = 144 steps.
//    Per step: acc[f] = bias + x_t@W_ih^T (4 K-tiles, A from LDS x-stage)
//                     + h@W_hh^T (8 K-tiles, A from LDS h), then gates.
//    W_hh resident: 48 frags/wave regs (AGPR) + 16 frags/wave LDS.
//    W_ih resident: 32 frags/wave regs. x staged 2-deep (4 KB/step), loads
//    issued one iteration ahead (T14 split: issue-early / ds_write-late).
//    BN sum/sumsq accumulated in-register at emit, quad-shuffle + atomics
//    at kernel end (krnl_stats' 134 MB re-read deleted).
//  K_norm: in-place normalize (training-mode biased stats).
// ws: stats only (4 KB).

typedef __attribute__((ext_vector_type(8))) short short8;
typedef __attribute__((ext_vector_type(4))) float floatx4;
typedef __attribute__((ext_vector_type(2))) unsigned int uintx2;
typedef __attribute__((ext_vector_type(4))) unsigned int uintx4;

#define S_LEN   4096
#define NCHUNK  1024
#define WARM_T  4
#define CPJ     32      // chunks emitted per jg group

__device__ __forceinline__ unsigned short f2bf(float f){
  unsigned u = __builtin_bit_cast(unsigned, f);
  u += 0x7FFFu + ((u >> 16) & 1u);
  return (unsigned short)(u >> 16);
}
__device__ __forceinline__ unsigned pack2(unsigned short a, unsigned short b){
  return (unsigned)a | ((unsigned)b << 16);
}
__device__ __forceinline__ float fsig(float x){
  return __builtin_amdgcn_rcpf(1.f + __expf(-x));
}
__device__ __forceinline__ float ftanh(float x){
  return 2.f * __builtin_amdgcn_rcpf(1.f + __expf(-2.f * x)) - 1.f;
}

// ---------------------------------------------------------------------------
// Fused recurrent kernel. grid 256 = bg(8) x jg(32), block 512 (8 waves).
// LDS (shorts): [Wlds 8w x 16frag x 512 = 65536][hlds 16 x 264 = 4224]
//               [xst 2 x 16 x 136 = 4352]  => 74112 shorts = 148224 B.
// Wave w owns hidden channels [32w,32w+32): frag f = type*2+sub,
// n = type*256 + w*32 + sub*16 + cl.  C layout: row(batch)=quad*4+r, col=cl.
// ---------------------------------------------------------------------------
__global__ __launch_bounds__(512, 2) void krnl_rec(
    const float* __restrict__ x,
    const float* __restrict__ Wih,
    const float* __restrict__ Whh,
    const float* __restrict__ bih,
    const float* __restrict__ bhh,
    float* __restrict__ out,
    float* __restrict__ stats)
{
  __shared__ unsigned short lds[74112];   // 148224 B < 160 KiB
  const int tid = threadIdx.x;
  const int w = tid >> 6, lane = tid & 63;
  const int cl = lane & 15, quad = lane >> 4;
  const int bg = blockIdx.x & 7;
  const int jg = blockIdx.x >> 3;
  const int js_emit = jg * CPJ;
  int js = js_emit - WARM_T; if (js < 0) js = 0;
  const int warm_steps = (js_emit - js) * 4;
  const int nsteps = warm_steps + CPJ * 4;
  const int js4 = js * 4;

  unsigned short* Wlds = lds + w * (16 * 512);
  unsigned short* hlds = lds + 8 * 16 * 512;           // short off 65536
  unsigned short* xst  = lds + 8 * 16 * 512 + 4224;    // short off 69760

  short8 Whreg[48];   // W_hh frag ids 16..63
  short8 Wireg[32];   // W_ih frag ids 0..31
  float bias[8];

  // --- W_hh fragments: ids 0..15 -> LDS (per-wave), 16..63 -> regs ---
#pragma unroll
  for (int kt = 0; kt < 8; ++kt) {
#pragma unroll
    for (int f = 0; f < 8; ++f) {
      const int type = f >> 1, sub = f & 1;
      const int n = type * 256 + w * 32 + sub * 16 + cl;
      const float* src = Whh + n * 256 + kt * 32 + quad * 8;
      floatx4 a0 = *(const floatx4*)(src);
      floatx4 a1 = *(const floatx4*)(src + 4);
      uintx4 u;
      u.x = pack2(f2bf(a0.x), f2bf(a0.y));
      u.y = pack2(f2bf(a0.z), f2bf(a0.w));
      u.z = pack2(f2bf(a1.x), f2bf(a1.y));
      u.w = pack2(f2bf(a1.z), f2bf(a1.w));
      const int id = kt * 8 + f;
      if (id < 16) {
        *(uintx4*)(Wlds + id * 512 + lane * 8) = u;
      } else {
        Whreg[id - 16] = __builtin_bit_cast(short8, u);
      }
    }
  }
  // --- W_ih fragments (K=128: kt 0..3) + fused bias ---
#pragma unroll
  for (int f = 0; f < 8; ++f) {
    const int type = f >> 1, sub = f & 1;
    const int n = type * 256 + w * 32 + sub * 16 + cl;
    bias[f] = bih[n] + bhh[n];
#pragma unroll
    for (int kt = 0; kt < 4; ++kt) {
      const float* src = Wih + n * 128 + kt * 32 + quad * 8;
      floatx4 a0 = *(const floatx4*)(src);
      floatx4 a1 = *(const floatx4*)(src + 4);
      uintx4 u;
      u.x = pack2(f2bf(a0.x), f2bf(a0.y));
      u.y = pack2(f2bf(a0.z), f2bf(a0.w));
      u.z = pack2(f2bf(a1.x), f2bf(a1.y));
      u.w = pack2(f2bf(a1.z), f2bf(a1.w));
      Wireg[kt * 8 + f] = __builtin_bit_cast(short8, u);
    }
  }
  for (int i = tid; i < 2112; i += 512) ((unsigned*)(hlds))[i] = 0u;
  float cst[8];
#pragma unroll
  for (int i = 0; i < 8; ++i) cst[i] = 0.f;

  // --- prologue x staging: steps 0 and 1 ---
  const int xrow = tid >> 5, xc4 = (tid & 31) * 4;
  const float* xbase = x + ((size_t)(bg * 16 + xrow) * S_LEN + js4) * 128 + xc4;
#pragma unroll
  for (int s0 = 0; s0 < 2; ++s0) {
    floatx4 v = *(const floatx4*)(xbase + (size_t)s0 * 128);
    uintx2 u;
    u.x = pack2(f2bf(v.x), f2bf(v.y));
    u.y = pack2(f2bf(v.z), f2bf(v.w));
    *(uintx2*)(xst + (s0 * 16 + xrow) * 136 + xc4) = u;
  }
  const float* xp = xbase + 256;   // next load target: step 2
  __syncthreads();

  float ssum[2]; float ssq[2];
  ssum[0] = ssum[1] = ssq[0] = ssq[1] = 0.f;
  const unsigned short* hA = hlds + cl * 264 + quad * 8;
  const unsigned short* xA = xst + cl * 136 + quad * 8;

  for (int s = 0; s < nsteps; ++s) {
    const int buf = s & 1;

    // (1) issue x loads for step s+2 (consumed after the barrier, T14 split)
    floatx4 xv;
    const bool havex = (s + 2 < nsteps);
    if (havex) xv = *(const floatx4*)(xp);

    // (2) MFMA: bias-init + x-part (4 kt) + h-part (8 kt)
    floatx4 acc[8];
#pragma unroll
    for (int f = 0; f < 8; ++f) {
      floatx4 z; z.x = bias[f]; z.y = bias[f]; z.z = bias[f]; z.w = bias[f];
      acc[f] = z;
    }
#pragma unroll
    for (int kt = 0; kt < 4; ++kt) {
      short8 a = *(const short8*)(xA + buf * 2176 + kt * 32);
#pragma unroll
      for (int f = 0; f < 8; ++f)
        acc[f] = __builtin_amdgcn_mfma_f32_16x16x32_bf16(a, Wireg[kt * 8 + f], acc[f], 0, 0, 0);
    }
#pragma unroll
    for (int kt = 0; kt < 8; ++kt) {
      short8 a = *(const short8*)(hA + kt * 32);
#pragma unroll
      for (int f = 0; f < 8; ++f) {
        const int id = kt * 8 + f;
        short8 b;
        if (id < 16) b = *(const short8*)(Wlds + id * 512 + lane * 8);
        else         b = Whreg[id - 16];
        acc[f] = __builtin_amdgcn_mfma_f32_16x16x32_bf16(a, b, acc[f], 0, 0, 0);
      }
    }
    __syncthreads();   // all A-reads of hlds/xst[buf] done before overwrite

    // (3) late half of x staging: convert + ds_write into xst[buf]
    if (havex) {
      uintx2 u;
      u.x = pack2(f2bf(xv.x), f2bf(xv.y));
      u.y = pack2(f2bf(xv.z), f2bf(xv.w));
      *(uintx2*)(xst + (buf * 16 + xrow) * 136 + xc4) = u;
      xp += 128;
    }

    // (4) gates + h update + emit
    const bool lastst = (s & 3) == 3;
    const bool emit = lastst && (s >= warm_steps);
    const float scale = lastst ? 0.5f : 1.f;
    const int j = js + (s >> 2);

#pragma unroll
    for (int sub = 0; sub < 2; ++sub) {
      float hr[4];
      const int fi = 0 + sub, ff = 2 + sub, fg = 4 + sub, fo = 6 + sub;
#pragma unroll
      for (int r = 0; r < 4; ++r) {
        float si = fsig(acc[fi][r]);
        float sf = fsig(acc[ff][r]);
        float so = fsig(acc[fo][r]);
        float tg = ftanh(acc[fg][r]);
        float cn = sf * cst[sub * 4 + r] + si * tg;
        float hn = so * ftanh(cn);
        cst[sub * 4 + r] = cn * scale;
        hr[r] = hn;
        hlds[(quad * 4 + r) * 264 + w * 32 + sub * 16 + cl] = f2bf(hn * scale);
      }
      if (emit) {
        const int ch = w * 32 + sub * 16 + cl;
        float a0 = 0.f, a1 = 0.f;
#pragma unroll
        for (int r = 0; r < 4; ++r) {
          const int b = bg * 16 + quad * 4 + r;
          out[(size_t)b * (NCHUNK * 256) + (size_t)j * 256 + ch] = hr[r];
          a0 += hr[r];
          a1 += hr[r] * hr[r];
        }
        ssum[sub] += a0;
        ssq[sub] += a1;
      }
    }
    __syncthreads();   // h/x writes visible before next step's A-reads
  }

  // --- fused BN stats: reduce over quad (batches), one atomic per channel ---
#pragma unroll
  for (int sub = 0; sub < 2; ++sub) {
    float a = ssum[sub], b = ssq[sub];
    a += __shfl_down(a, 32); a += __shfl_down(a, 16);
    b += __shfl_down(b, 32); b += __shfl_down(b, 16);
    if (quad == 0) {
      const int ch = w * 32 + sub * 16 + cl;
      atomicAdd(&stats[ch], a);
      atomicAdd(&stats[256 + ch], b);
    }
  }
}

// ---------------------------------------------------------------------------
// stats zero + in-place BatchNorm normalize (biased batch stats).
// stats[0..255]=sum, [256..511]=sumsq.
// ---------------------------------------------------------------------------
__global__ void krnl_zero(float* __restrict__ stats){ stats[threadIdx.x] = 0.f; }

__global__ __launch_bounds__(256, 4) void krnl_norm(
    float* __restrict__ out, const float* __restrict__ stats,
    const float* __restrict__ gamma, const float* __restrict__ beta)
{
  const int tid = threadIdx.x;
  const int rl = tid >> 6, c4 = (tid & 63) * 4;
  const float inv = 1.f / 131072.f;
  float sc[4], sh[4];
#pragma unroll
  for (int k = 0; k < 4; ++k) {
    const int c = c4 + k;
    const float mean = stats[c] * inv;
    const float var = stats[256 + c] * inv - mean * mean;
    const float s = rsqrtf(var + 1e-5f) * gamma[c];
    sc[k] = s; sh[k] = beta[c] - mean * s;
  }
  for (int it = 0; it < 16; ++it) {
    const size_t r = (size_t)blockIdx.x * 64 + it * 4 + rl;
    float* p = out + r * 256 + c4;
    floatx4 v = *(const floatx4*)(p);
    floatx4 o;
    o.x = v.x * sc[0] + sh[0];
    o.y = v.y * sc[1] + sh[1];
    o.z = v.z * sc[2] + sh[2];
    o.w = v.w * sc[3] + sh[3];
    *(floatx4*)(p) = o;
  }
}

extern "C" void kernel_launch(void* const* d_in, const int* in_sizes, int n_in,
                              void* d_out, int out_size, void* d_ws, size_t ws_size,
                              hipStream_t stream) {
  const float* x     = (const float*)d_in[0];
  const float* Wih   = (const float*)d_in[1];
  const float* Whh   = (const float*)d_in[2];
  const float* bih   = (const float*)d_in[3];
  const float* bhh   = (const float*)d_in[4];
  const float* gamma = (const float*)d_in[5];
  const float* beta  = (const float*)d_in[6];
  float* out = (float*)d_out;
  float* stats = (float*)d_ws;

  hipLaunchKernelGGL(krnl_zero, dim3(1), dim3(512), 0, stream, stats);
  hipLaunchKernelGGL(krnl_rec, dim3(256), dim3(512), 0, stream,
                     x, Wih, Whh, bih, bhh, out, stats);
  hipLaunchKernelGGL(krnl_norm, dim3(2048), dim3(256), 0, stream,
                     out, stats, gamma, beta);
}

// Round 4
// 1697.757 us; speedup vs baseline: 2.1535x; 2.1535x over previous
//
#include <hip/hip_runtime.h>

// Receptor LSTM on MI355X — two-kernel plan, adaptive workspace. f32 OUTPUT.
//  R4 = R3 resubmitted verbatim (R3 bench died in infra: "container failed
//  twice", no pytest/profile ran; audit found no race/hang surface).
//  R3 = R0 structure exactly (R1/R2 both regressed and are reverted), with ONE
//  change: krnl_xgemm keeps its 64-t-per-WG serial loop (same grid, same t
//  order, same store pattern => same L3 residue that krnl_rec depends on) but
//  double-buffers the x LDS stage and prefetches x(t+1) into regs, cutting the
//  per-t cost from ~2 barriers + unhidden global latency to 1 barrier with the
//  load in flight across it. Bias folded into MFMA C-init (verified R1/R2).
//  K2 krnl_rec: truncated-history parallel LSTM (identical to R0-measured).
//  K3 stats / K4 normalize: training-mode BatchNorm, identical to R0.
// ws layout: [stats 4 KB][xfrag ring (32E+4) MB], E picked from ws_size.

typedef __attribute__((ext_vector_type(8))) short short8;
typedef __attribute__((ext_vector_type(4))) float floatx4;
typedef __attribute__((ext_vector_type(2))) unsigned int uintx2;
typedef __attribute__((ext_vector_type(4))) unsigned int uintx4;

#define S_LEN   4096
#define NCHUNK  1024
#define WARM_T  4

__device__ __forceinline__ unsigned short f2bf(float f){
  unsigned u = __builtin_bit_cast(unsigned, f);
  u += 0x7FFFu + ((u >> 16) & 1u);
  return (unsigned short)(u >> 16);
}
__device__ __forceinline__ float bf2f(unsigned short h){
  unsigned u = ((unsigned)h) << 16;
  return __builtin_bit_cast(float, u);
}
__device__ __forceinline__ unsigned pack2(unsigned short a, unsigned short b){
  return (unsigned)a | ((unsigned)b << 16);
}
__device__ __forceinline__ float fsig(float x){
  return __builtin_amdgcn_rcpf(1.f + __expf(-x));
}
__device__ __forceinline__ float ftanh(float x){
  return 2.f * __builtin_amdgcn_rcpf(1.f + __expf(-2.f * x)) - 1.f;
}

// ---------------------------------------------------------------------------
// K1: xpart GEMM. grid = 8 bg * ntiles (64 timesteps each), block 512 (8 waves).
// Wave w owns hidden channels [32w,32w+32): frag f = type*2+sub,
// n = type*256 + w*32 + sub*16 + cl.
// Output frag layout: [t_local][bg][w][lane][32 shorts] (64 B/lane contiguous).
// xlds double-buffered (2 x 4352 B), x(t+1) prefetched into regs before
// the single per-t barrier. Race-free: iteration t's reads of buf are ordered
// against iteration t+2's writes of buf by the barrier at t+1.
// ---------------------------------------------------------------------------
__global__ __launch_bounds__(512, 2) void krnl_xgemm(
    const float* __restrict__ x, const float* __restrict__ Wih,
    const float* __restrict__ bih, const float* __restrict__ bhh,
    unsigned short* __restrict__ xfrag, int tbase, int tcount)
{
  __shared__ unsigned short xlds[2 * 16 * 136];   // 8704 B
  const int tid = threadIdx.x;
  const int w = tid >> 6, lane = tid & 63;
  const int cl = lane & 15, quad = lane >> 4;
  const int bg = blockIdx.x & 7, tslice = blockIdx.x >> 3;

  short8 Bw[32];
  float bias[8];
#pragma unroll
  for (int f = 0; f < 8; ++f) {
    const int type = f >> 1, sub = f & 1;
    const int n = type * 256 + w * 32 + sub * 16 + cl;
    bias[f] = bih[n] + bhh[n];
#pragma unroll
    for (int kt = 0; kt < 4; ++kt) {
      const float* src = Wih + n * 128 + kt * 32 + quad * 8;
      floatx4 a0 = *(const floatx4*)(src);
      floatx4 a1 = *(const floatx4*)(src + 4);
      uintx4 u;
      u.x = pack2(f2bf(a0.x), f2bf(a0.y));
      u.y = pack2(f2bf(a0.z), f2bf(a0.w));
      u.z = pack2(f2bf(a1.x), f2bf(a1.y));
      u.w = pack2(f2bf(a1.z), f2bf(a1.w));
      Bw[kt * 8 + f] = __builtin_bit_cast(short8, u);
    }
  }

  const int row = tid >> 5, c4 = (tid & 31) * 4;
  const float* xsrc = x + ((size_t)(bg * 16 + row) * S_LEN) * 128 + c4;

  const int tl_beg = tslice * 64;
  int tl_end = tl_beg + 64;
  if (tl_end > tcount) tl_end = tcount;

  // preload x(t0) into regs
  const float* xq = xsrc + (size_t)(tbase + tl_beg) * 128;
  floatx4 xv = *(const floatx4*)(xq);

  for (int tl = tl_beg; tl < tl_end; ++tl) {
    const int buf = tl & 1;
    // stage current t into LDS buffer
    uintx2 u;
    u.x = pack2(f2bf(xv.x), f2bf(xv.y));
    u.y = pack2(f2bf(xv.z), f2bf(xv.w));
    *(uintx2*)(xlds + (buf * 16 + row) * 136 + c4) = u;
    // prefetch next t (in flight across barrier + MFMA + store)
    if (tl + 1 < tl_end) {
      xq += 128;
      xv = *(const floatx4*)(xq);
    }
    __syncthreads();

    const unsigned short* hA = xlds + (buf * 16 + cl) * 136 + quad * 8;
    floatx4 acc[8];
#pragma unroll
    for (int kt = 0; kt < 4; ++kt) {
      short8 a = *(const short8*)(hA + kt * 32);
#pragma unroll
      for (int f = 0; f < 8; ++f) {
        if (kt == 0) {
          // bias folded into C-init: all 4 rows of a frag share channel n
          floatx4 z; z.x = bias[f]; z.y = bias[f]; z.z = bias[f]; z.w = bias[f];
          acc[f] = __builtin_amdgcn_mfma_f32_16x16x32_bf16(a, Bw[f], z, 0, 0, 0);
        } else {
          acc[f] = __builtin_amdgcn_mfma_f32_16x16x32_bf16(a, Bw[kt * 8 + f], acc[f], 0, 0, 0);
        }
      }
    }

    unsigned short* dst = xfrag + ((((size_t)tl * 8 + bg) * 8 + w) * 64 + lane) * 32;
#pragma unroll
    for (int p = 0; p < 4; ++p) {
      const int f0 = p * 2, f1 = p * 2 + 1;
      uintx4 o;
      o.x = pack2(f2bf(acc[f0].x), f2bf(acc[f0].y));
      o.y = pack2(f2bf(acc[f0].z), f2bf(acc[f0].w));
      o.z = pack2(f2bf(acc[f1].x), f2bf(acc[f1].y));
      o.w = pack2(f2bf(acc[f1].z), f2bf(acc[f1].w));
      *(uintx4*)(dst + p * 8) = o;
    }
    // no second barrier: next iteration writes the other buffer; reuse of this
    // buffer is fenced by the next iteration's barrier.
  }
}

// ---------------------------------------------------------------------------
// K2: recurrent kernel. grid 256 = bg(8) x jg_local(32), block 512 (8 waves).
// Static LDS: per-wave W_hh frag ids 0..17 (9216 shorts/wave), then h[16][264].
// Emits raw f32 h into d_out [b][j][ch].  (Identical to the R0-measured rec.)
// ---------------------------------------------------------------------------
__global__ __launch_bounds__(512, 2) void krnl_rec(
    const float* __restrict__ Whh,
    const unsigned short* __restrict__ xfrag,
    float* __restrict__ out,
    int tbase, int jg0, int E)
{
  __shared__ unsigned short lds[77952];   // 155904 B < 160 KiB
  const int tid = threadIdx.x;
  const int w = tid >> 6, lane = tid & 63;
  const int cl = lane & 15, quad = lane >> 4;
  const int bg = blockIdx.x & 7;
  const int jg = jg0 + (blockIdx.x >> 3);
  const int js_emit = jg * E;
  int js = js_emit - WARM_T; if (js < 0) js = 0;
  const int warm_steps = (js_emit - js) * 4;
  const int nsteps = warm_steps + E * 4;

  unsigned short* Wlds = lds + w * (18 * 512);
  unsigned short* hlds = lds + 8 * 18 * 512;   // short offset 73728

  short8 Wreg[46];
#pragma unroll
  for (int kt = 0; kt < 8; ++kt) {
#pragma unroll
    for (int f = 0; f < 8; ++f) {
      const int type = f >> 1, sub = f & 1;
      const int n = type * 256 + w * 32 + sub * 16 + cl;
      const float* src = Whh + n * 256 + kt * 32 + quad * 8;
      floatx4 a0 = *(const floatx4*)(src);
      floatx4 a1 = *(const floatx4*)(src + 4);
      uintx4 u;
      u.x = pack2(f2bf(a0.x), f2bf(a0.y));
      u.y = pack2(f2bf(a0.z), f2bf(a0.w));
      u.z = pack2(f2bf(a1.x), f2bf(a1.y));
      u.w = pack2(f2bf(a1.z), f2bf(a1.w));
      const int id = kt * 8 + f;
      if (id < 18) {
        *(uintx4*)(Wlds + id * 512 + lane * 8) = u;
      } else {
        Wreg[id - 18] = __builtin_bit_cast(short8, u);
      }
    }
  }
  for (int i = tid; i < 2112; i += 512) ((unsigned*)(hlds))[i] = 0u;
  float cst[8];
#pragma unroll
  for (int i = 0; i < 8; ++i) cst[i] = 0.f;
  __syncthreads();

  const int tl0 = js * 4 - tbase;   // >= 0 by construction
  const unsigned short* xptr =
      xfrag + (((size_t)tl0 * 8 + bg) * 8 + w) * 2048 + lane * 32;
  const unsigned short* hA = hlds + cl * 264 + quad * 8;

  for (int s = 0; s < nsteps; ++s) {
    uintx4 xs0 = *(const uintx4*)(xptr);
    uintx4 xs1 = *(const uintx4*)(xptr + 8);
    uintx4 xs2 = *(const uintx4*)(xptr + 16);
    uintx4 xs3 = *(const uintx4*)(xptr + 24);

    floatx4 acc[8];
#pragma unroll
    for (int kt = 0; kt < 8; ++kt) {
      short8 a = *(const short8*)(hA + kt * 32);
#pragma unroll
      for (int f = 0; f < 8; ++f) {
        const int id = kt * 8 + f;
        short8 b;
        if (id < 18) b = *(const short8*)(Wlds + id * 512 + lane * 8);
        else         b = Wreg[id - 18];
        if (kt == 0) {
          floatx4 z; z.x = 0.f; z.y = 0.f; z.z = 0.f; z.w = 0.f;
          acc[f] = __builtin_amdgcn_mfma_f32_16x16x32_bf16(a, b, z, 0, 0, 0);
        } else {
          acc[f] = __builtin_amdgcn_mfma_f32_16x16x32_bf16(a, b, acc[f], 0, 0, 0);
        }
      }
    }
    __syncthreads();   // all A-reads of hlds done before overwrite

    unsigned xd[16];
    xd[0]  = xs0.x; xd[1]  = xs0.y; xd[2]  = xs0.z; xd[3]  = xs0.w;
    xd[4]  = xs1.x; xd[5]  = xs1.y; xd[6]  = xs1.z; xd[7]  = xs1.w;
    xd[8]  = xs2.x; xd[9]  = xs2.y; xd[10] = xs2.z; xd[11] = xs2.w;
    xd[12] = xs3.x; xd[13] = xs3.y; xd[14] = xs3.z; xd[15] = xs3.w;

    const bool lastst = (s & 3) == 3;
    const bool emit = lastst && (s >= warm_steps);
    const float scale = lastst ? 0.5f : 1.f;
    const int j = js + (s >> 2);

#pragma unroll
    for (int sub = 0; sub < 2; ++sub) {
      float hr[4];
      const int fi = 0 + sub, ff = 2 + sub, fg = 4 + sub, fo = 6 + sub;
#pragma unroll
      for (int r = 0; r < 4; ++r) {
        const int dsel = r >> 1, hsel = (r & 1) * 16;
        float xi = bf2f((unsigned short)((xd[fi * 2 + dsel] >> hsel) & 0xFFFF));
        float xf = bf2f((unsigned short)((xd[ff * 2 + dsel] >> hsel) & 0xFFFF));
        float xg = bf2f((unsigned short)((xd[fg * 2 + dsel] >> hsel) & 0xFFFF));
        float xo = bf2f((unsigned short)((xd[fo * 2 + dsel] >> hsel) & 0xFFFF));
        float vi = acc[fi][r] + xi;
        float vf = acc[ff][r] + xf;
        float vg = acc[fg][r] + xg;
        float vo = acc[fo][r] + xo;
        float si = fsig(vi), sf = fsig(vf), so = fsig(vo);
        float tg = ftanh(vg);
        float cn = sf * cst[sub * 4 + r] + si * tg;
        float hn = so * ftanh(cn);
        cst[sub * 4 + r] = cn * scale;
        hr[r] = hn;
        hlds[(quad * 4 + r) * 264 + w * 32 + sub * 16 + cl] = f2bf(hn * scale);
      }
      if (emit) {
        const int ch = w * 32 + sub * 16 + cl;
#pragma unroll
        for (int r = 0; r < 4; ++r) {
          const int b = bg * 16 + quad * 4 + r;
          out[(size_t)b * (NCHUNK * 256) + (size_t)j * 256 + ch] = hr[r];
        }
      }
    }
    __syncthreads();   // h writes visible before next step's A-reads
    xptr += 131072;    // one timestep: 8 bg * 8 w * 64 lanes * 32 shorts
  }
}

// ---------------------------------------------------------------------------
// K3/K4: BatchNorm (biased batch stats) over d_out [b][j][ch] f32, then
// in-place normalize. stats[0..255]=sum, [256..511]=sumsq.
// ---------------------------------------------------------------------------
__global__ void krnl_zero(float* __restrict__ stats){ stats[threadIdx.x] = 0.f; }

__global__ __launch_bounds__(256, 4) void krnl_stats(
    const float* __restrict__ out, float* __restrict__ stats)
{
  __shared__ float lsum[4][256];
  __shared__ float lsq[4][256];
  const int tid = threadIdx.x;
  const int brow = tid >> 6, c4 = (tid & 63) * 4;
  float s0=0.f,s1=0.f,s2=0.f,s3=0.f, q0=0.f,q1=0.f,q2=0.f,q3=0.f;
  for (int jj = 0; jj < 8; ++jj) {
    const int j = blockIdx.x * 8 + jj;
    for (int b = brow; b < 128; b += 4) {
      floatx4 v = *(const floatx4*)(out + ((size_t)b * NCHUNK + j) * 256 + c4);
      s0 += v.x; s1 += v.y; s2 += v.z; s3 += v.w;
      q0 += v.x*v.x; q1 += v.y*v.y; q2 += v.z*v.z; q3 += v.w*v.w;
    }
  }
  lsum[brow][c4+0] = s0; lsum[brow][c4+1] = s1;
  lsum[brow][c4+2] = s2; lsum[brow][c4+3] = s3;
  lsq[brow][c4+0] = q0; lsq[brow][c4+1] = q1;
  lsq[brow][c4+2] = q2; lsq[brow][c4+3] = q3;
  __syncthreads();
  float ts = 0.f, tq = 0.f;
#pragma unroll
  for (int br = 0; br < 4; ++br) { ts += lsum[br][tid]; tq += lsq[br][tid]; }
  atomicAdd(&stats[tid], ts);
  atomicAdd(&stats[256 + tid], tq);
}

__global__ __launch_bounds__(256, 4) void krnl_norm(
    float* __restrict__ out, const float* __restrict__ stats,
    const float* __restrict__ gamma, const float* __restrict__ beta)
{
  const int tid = threadIdx.x;
  const int rl = tid >> 6, c4 = (tid & 63) * 4;
  const float inv = 1.f / 131072.f;
  float sc[4], sh[4];
#pragma unroll
  for (int k = 0; k < 4; ++k) {
    const int c = c4 + k;
    const float mean = stats[c] * inv;
    const float var = stats[256 + c] * inv - mean * mean;
    const float s = rsqrtf(var + 1e-5f) * gamma[c];
    sc[k] = s; sh[k] = beta[c] - mean * s;
  }
  for (int it = 0; it < 16; ++it) {
    const size_t r = (size_t)blockIdx.x * 64 + it * 4 + rl;
    float* p = out + r * 256 + c4;
    floatx4 v = *(const floatx4*)(p);
    floatx4 o;
    o.x = v.x * sc[0] + sh[0];
    o.y = v.y * sc[1] + sh[1];
    o.z = v.z * sc[2] + sh[2];
    o.w = v.w * sc[3] + sh[3];
    *(floatx4*)(p) = o;
  }
}

extern "C" void kernel_launch(void* const* d_in, const int* in_sizes, int n_in,
                              void* d_out, int out_size, void* d_ws, size_t ws_size,
                              hipStream_t stream) {
  const float* x     = (const float*)d_in[0];
  const float* Wih   = (const float*)d_in[1];
  const float* Whh   = (const float*)d_in[2];
  const float* bih   = (const float*)d_in[3];
  const float* bhh   = (const float*)d_in[4];
  const float* gamma = (const float*)d_in[5];
  const float* beta  = (const float*)d_in[6];
  float* out = (float*)d_out;

  float* stats = (float*)d_ws;
  unsigned short* xfrag = (unsigned short*)((char*)d_ws + 4096);
  const size_t avail = ws_size > 4096 ? ws_size - 4096 : 0;

  int E = 1;
  if      (avail >= ((size_t)(32 * 32 + 4)) << 20) E = 32;
  else if (avail >= ((size_t)(32 * 16 + 4)) << 20) E = 16;
  else if (avail >= ((size_t)(32 * 8  + 4)) << 20) E = 8;
  else if (avail >= ((size_t)(32 * 4  + 4)) << 20) E = 4;
  else if (avail >= ((size_t)(32 * 2  + 4)) << 20) E = 2;
  const int P = NCHUNK / (32 * E);

  hipLaunchKernelGGL(krnl_zero, dim3(1), dim3(512), 0, stream, stats);
  for (int p = 0; p < P; ++p) {
    const int c0 = p * 32 * E;                       // first emitted chunk
    const int cb = (c0 >= WARM_T) ? c0 - WARM_T : 0; // first buffered chunk
    const int tbase = cb * 4;
    const int tend = (c0 + 32 * E) * 4;
    const int tcount = tend - tbase;
    const int ntiles = (tcount + 63) / 64;
    hipLaunchKernelGGL(krnl_xgemm, dim3(8 * ntiles), dim3(512), 0, stream,
                       x, Wih, bih, bhh, xfrag, tbase, tcount);
    hipLaunchKernelGGL(krnl_rec, dim3(256), dim3(512), 0, stream,
                       Whh, xfrag, out, tbase, p * 32, E);
  }
  hipLaunchKernelGGL(krnl_stats, dim3(128), dim3(256), 0, stream, out, stats);
  hipLaunchKernelGGL(krnl_norm, dim3(2048), dim3(256), 0, stream, out, stats, gamma, beta);
}